// Round 3
// baseline (192.878 us; speedup 1.0000x reference)
//
#include <hip/hip_runtime.h>

// BLAMem: truncated tensor-algebra (depth 4, C=8) log-signature memory.
// Identities:
//  (1) BCH-prefix-scan of chunk log-sigs == ta_log of ta_mul-prefix-scan of chunk sigs.
//  (2) Chen fold over a 16-step chunk has a closed parallel form:
//      L4 = sum_t G[t][ijk]*d_t[l],  G[t] = L3ex[t] + d_t[k]*(L2ex[t]/2 + d_t[j]*(P1ex[t]/6 + d_t[i]/24))
//      with P1ex/L2ex/L3ex exclusive prefixes computable per-thread in registers.

#define MEM   4680   // 8 + 64 + 512 + 4096
#define OFF2  8
#define OFF3  72
#define OFF4  584
#define NCH   128
#define NG    32     // groups per batch
#define LCH   4      // chunks per group
#define TLEN  2048
#define GSTR  20     // G-table stride (floats): conflict-free b128 reads across kq

// ------------------------------------------------ group sigs (parallel-prefix Chen)
// block=(b,g). For c=0..3: chunk-local sig via closed form, then fold into running
// group product A (LDS); write cumulative snapshot Q[(blk*4+c)].
__global__ __launch_bounds__(256) void group_sig_kernel(const float* __restrict__ x,
                                                        float* __restrict__ Q) {
    int blk = blockIdx.x;
    int b = blk >> 5, g = blk & 31;
    int tid = threadIdx.x;
    int lane = tid & 63, w = tid >> 6;
    int kq = lane >> 3, lq = lane & 7;

    __shared__ float sInc[64 * 8];
    __shared__ __attribute__((aligned(16))) float sG[512 * GSTR];  // 40 KB
    __shared__ float sA[MEM];
    __shared__ float loc3[512];
    __shared__ float loc2[64];
    __shared__ float loc1[8];

    for (int e = tid; e < 64 * 8; e += 256) {
        int s = e >> 3, c = e & 7;
        int t = g * 64 + s;
        float v;
        if (c < 7) {
            float cur  = x[(b * TLEN + t) * 7 + c];
            float prev = (t > 0) ? x[(b * TLEN + t - 1) * 7 + c] : 0.0f;
            v = cur - prev;
        } else {
            v = (t > 0) ? (1.0f / 2047.0f) : 0.0f;
        }
        sInc[e] = v;
    }
    for (int m = tid; m < MEM; m += 256) sA[m] = 0.0f;
    __syncthreads();

    for (int c = 0; c < LCH; c++) {
        const float* dch = &sInc[c * 128];  // 16 steps x 8 channels

        // --- G pass: exclusive-prefix recurrences in registers, 2 positions/thread
        int pos1 = tid, pos2 = tid + 256;
        int i1 = pos1 >> 6, j1 = (pos1 >> 3) & 7, k1 = pos1 & 7;
        int i2 = pos2 >> 6;  // j,k same as pos1
        float p1a = 0.0f, l2a = 0.0f, l3a = 0.0f;
        float p1b = 0.0f, l2b = 0.0f, l3b = 0.0f;
        float ga[16], gb[16];
#pragma unroll
        for (int t = 0; t < 16; t++) {
            float di1 = dch[t * 8 + i1], di2 = dch[t * 8 + i2];
            float dj = dch[t * 8 + j1], dk = dch[t * 8 + k1];
            ga[t] = l3a + dk * (l2a * 0.5f + dj * (p1a * (1.0f / 6.0f) + di1 * (1.0f / 24.0f)));
            gb[t] = l3b + dk * (l2b * 0.5f + dj * (p1b * (1.0f / 6.0f) + di2 * (1.0f / 24.0f)));
            l3a += dk * (l2a + dj * (p1a * 0.5f + di1 * (1.0f / 6.0f)));
            l3b += dk * (l2b + dj * (p1b * 0.5f + di2 * (1.0f / 6.0f)));
            l2a += p1a * dj + di1 * dj * 0.5f;
            l2b += p1b * dj + di2 * dj * 0.5f;
            p1a += di1;
            p1b += di2;
        }
        {
            float4* gp1 = (float4*)&sG[pos1 * GSTR];
            float4* gp2 = (float4*)&sG[pos2 * GSTR];
            gp1[0] = make_float4(ga[0], ga[1], ga[2], ga[3]);
            gp1[1] = make_float4(ga[4], ga[5], ga[6], ga[7]);
            gp1[2] = make_float4(ga[8], ga[9], ga[10], ga[11]);
            gp1[3] = make_float4(ga[12], ga[13], ga[14], ga[15]);
            gp2[0] = make_float4(gb[0], gb[1], gb[2], gb[3]);
            gp2[1] = make_float4(gb[4], gb[5], gb[6], gb[7]);
            gp2[2] = make_float4(gb[8], gb[9], gb[10], gb[11]);
            gp2[3] = make_float4(gb[12], gb[13], gb[14], gb[15]);
        }
        loc3[pos1] = l3a;
        loc3[pos2] = l3b;
        if (k1 == 0) { loc2[pos1 >> 3] = l2a; loc2[pos2 >> 3] = l2b; }
        if ((pos1 & 63) == 0) { loc1[i1] = p1a; loc1[i2] = p1b; }
        __syncthreads();

        // --- L4 sum + ta_mul with running A (all into registers)
        float dl[16];
#pragma unroll
        for (int t = 0; t < 16; t++) dl[t] = dch[t * 8 + lq];

        float r4[16];
#pragma unroll
        for (int r = 0; r < 16; r++) {
            int row = w + 4 * r;
            int i = row >> 3, j = row & 7;
            int m = row * 64 + lane;
            const float4* gp = (const float4*)&sG[(row * 8 + kq) * GSTR];
            float4 g0 = gp[0], g1 = gp[1], g2 = gp[2], g3 = gp[3];
            float acc = g0.x * dl[0] + g0.y * dl[1] + g0.z * dl[2] + g0.w * dl[3]
                      + g1.x * dl[4] + g1.y * dl[5] + g1.z * dl[6] + g1.w * dl[7]
                      + g2.x * dl[8] + g2.y * dl[9] + g2.z * dl[10] + g2.w * dl[11]
                      + g3.x * dl[12] + g3.y * dl[13] + g3.z * dl[14] + g3.w * dl[15];
            r4[r] = sA[OFF4 + m] + acc
                  + sA[i] * loc3[j * 64 + lane]
                  + sA[OFF2 + row] * loc2[lane]
                  + sA[OFF3 + row * 8 + kq] * loc1[lq];
        }
        float r3[2];
#pragma unroll
        for (int q = 0; q < 2; q++) {
            int m3 = tid + 256 * q;
            float l3v = (q == 0) ? l3a : l3b;
            r3[q] = sA[OFF3 + m3] + l3v
                  + sA[m3 >> 6] * loc2[m3 & 63]
                  + sA[OFF2 + (m3 >> 3)] * loc1[m3 & 7];
        }
        float r2v = 0.0f, r1v = 0.0f;
        if (tid < 64) r2v = sA[OFF2 + tid] + loc2[tid] + sA[tid >> 3] * loc1[tid & 7];
        if (tid < 8)  r1v = sA[tid] + loc1[tid];
        __syncthreads();  // all reads of old A done

        size_t qbase = (size_t)(blk * LCH + c) * MEM;
#pragma unroll
        for (int r = 0; r < 16; r++) {
            int row = w + 4 * r;
            int m = row * 64 + lane;
            sA[OFF4 + m] = r4[r];
            Q[qbase + OFF4 + m] = r4[r];
        }
        sA[OFF3 + tid] = r3[0];       Q[qbase + OFF3 + tid] = r3[0];
        sA[OFF3 + 256 + tid] = r3[1]; Q[qbase + OFF3 + 256 + tid] = r3[1];
        if (tid < 64) { sA[OFF2 + tid] = r2v; Q[qbase + OFF2 + tid] = r2v; }
        if (tid < 8)  { sA[tid] = r1v;        Q[qbase + tid] = r1v; }
        __syncthreads();
    }
}

// ------------------------------------------------ serial fold over group totals
// block=b. Writes EXCLUSIVE prefixes P[b][g] (P[b][0]=0=identity), folding the
// c=3 (group-total) slices of Q.
__global__ __launch_bounds__(256) void scan_fold_kernel(const float* __restrict__ Q,
                                                        float* __restrict__ P) {
    int b = blockIdx.x;
    int tid = threadIdx.x;
    int lane = tid & 63, w = tid >> 6;
    int kq = lane >> 3, lq = lane & 7;

    __shared__ float sA[MEM], sB[MEM];
    for (int m = tid; m < MEM; m += 256) sA[m] = 0.0f;
    __syncthreads();

    for (int g = 0; g < NG; g++) {
        // write exclusive prefix
        {
            size_t pbase = (size_t)(b * NG + g) * MEM;
            const float4* src = (const float4*)sA;
            float4* dst = (float4*)(P + pbase);
            for (int m = tid; m < MEM / 4; m += 256) dst[m] = src[m];
        }
        // load group total
        {
            size_t qbase = (size_t)((b * NG + g) * LCH + (LCH - 1)) * MEM;
            const float4* src = (const float4*)(Q + qbase);
            float4* dst = (float4*)sB;
            for (int m = tid; m < MEM / 4; m += 256) dst[m] = src[m];
        }
        __syncthreads();

        float b1l = sB[lq];
        float b2lane = sB[OFF2 + lane];
        float r4[16];
#pragma unroll
        for (int r = 0; r < 16; r++) {
            int row = w + 4 * r;
            int i = row >> 3, j = row & 7;
            int m = row * 64 + lane;
            r4[r] = sA[OFF4 + m] + sB[OFF4 + m]
                  + sA[i] * sB[OFF3 + j * 64 + lane]
                  + sA[OFF2 + row] * b2lane
                  + sA[OFF3 + row * 8 + kq] * b1l;
        }
        float r3[2];
#pragma unroll
        for (int q = 0; q < 2; q++) {
            int m3 = tid + 256 * q;
            r3[q] = sA[OFF3 + m3] + sB[OFF3 + m3]
                  + sA[m3 >> 6] * sB[OFF2 + (m3 & 63)]
                  + sA[OFF2 + (m3 >> 3)] * sB[m3 & 7];
        }
        float r2v = 0.0f, r1v = 0.0f;
        if (tid < 64) r2v = sA[OFF2 + tid] + sB[OFF2 + tid] + sA[tid >> 3] * sB[tid & 7];
        if (tid < 8)  r1v = sA[tid] + sB[tid];
        __syncthreads();

#pragma unroll
        for (int r = 0; r < 16; r++) {
            int row = w + 4 * r;
            sA[OFF4 + row * 64 + lane] = r4[r];
        }
        sA[OFF3 + tid] = r3[0];
        sA[OFF3 + 256 + tid] = r3[1];
        if (tid < 64) sA[OFF2 + tid] = r2v;
        if (tid < 8)  sA[tid] = r1v;
        __syncthreads();
    }
}

// ------------------------------------------------ apply prefix + log + pooled atomics
// block=(b,g): for c=0..3: R = P[b][g] (x) Q[b][g][c]; accumulate ta_log(R);
// atomicAdd scaled partial into pooled[b].
__global__ __launch_bounds__(256) void apply_log_pool_kernel(const float* __restrict__ Q,
                                                             const float* __restrict__ P,
                                                             float* __restrict__ pooled) {
    int blk = blockIdx.x;
    int b = blk >> 5;
    int tid = threadIdx.x;
    int lane = tid & 63, w = tid >> 6;
    int kq = lane >> 3, lq = lane & 7;

    __shared__ float sA[MEM];     // group exclusive prefix
    __shared__ float sB[MEM];     // Q chunk (cumulative within group)
    __shared__ float sR[OFF4];    // R levels 1..3
    __shared__ float sP23[512];   // (R^2) level 3

    {
        size_t pbase = (size_t)blk * MEM;
        const float4* src = (const float4*)(P + pbase);
        float4* dst = (float4*)sA;
        for (int m = tid; m < MEM / 4; m += 256) dst[m] = src[m];
    }

    float pool4[16];
#pragma unroll
    for (int r = 0; r < 16; r++) pool4[r] = 0.0f;
    float pool3[2] = {0.0f, 0.0f};
    float pool2 = 0.0f, pool1 = 0.0f;

    for (int c = 0; c < LCH; c++) {
        __syncthreads();
        {
            size_t baseQ = (size_t)(blk * LCH + c) * MEM;
            const float4* src = (const float4*)(Q + baseQ);
            float4* dst = (float4*)sB;
            for (int m = tid; m < MEM / 4; m += 256) dst[m] = src[m];
        }
        __syncthreads();

        float b1l = sB[lq];
        float b2lane = sB[OFF2 + lane];

        float r1 = 0.0f, r2v = 0.0f;
        float r3v[2];
#pragma unroll
        for (int q = 0; q < 2; q++) {
            int m3 = tid + 256 * q;
            r3v[q] = sA[OFF3 + m3] + sB[OFF3 + m3]
                   + sA[m3 >> 6] * sB[OFF2 + (m3 & 63)]
                   + sA[OFF2 + (m3 >> 3)] * sB[m3 & 7];
        }
        if (tid < 64) r2v = sA[OFF2 + tid] + sB[OFF2 + tid] + sA[tid >> 3] * sB[tid & 7];
        if (tid < 8)  r1 = sA[tid] + sB[tid];

        float r4[16];
#pragma unroll
        for (int r = 0; r < 16; r++) {
            int row = w + 4 * r;
            int i = row >> 3, j = row & 7;
            int m = row * 64 + lane;
            r4[r] = sA[OFF4 + m] + sB[OFF4 + m]
                  + sA[i] * sB[OFF3 + j * 64 + lane]
                  + sA[OFF2 + row] * b2lane
                  + sA[OFF3 + row * 8 + kq] * b1l;
        }

#pragma unroll
        for (int q = 0; q < 2; q++) sR[OFF3 + tid + 256 * q] = r3v[q];
        if (tid < 64) sR[OFF2 + tid] = r2v;
        if (tid < 8)  sR[tid] = r1;
        __syncthreads();

#pragma unroll
        for (int q = 0; q < 2; q++) {
            int m3 = tid + 256 * q;
            int i = m3 >> 6;
            sP23[m3] = sR[i] * sR[OFF2 + (m3 & 63)]
                     + sR[OFF2 + i * 8 + ((m3 >> 3) & 7)] * sR[m3 & 7];
        }
        __syncthreads();

        float s1l = sR[lq];
        float s2lane = sR[OFF2 + lane];
        float p22lane = sR[kq] * sR[lq];
#pragma unroll
        for (int r = 0; r < 16; r++) {
            int row = w + 4 * r;
            int i = row >> 3, j = row & 7;
            float s1i = sR[i];
            float p24 = s1i * sR[OFF3 + j * 64 + lane] + sR[OFF2 + row] * s2lane
                      + sR[OFF3 + row * 8 + kq] * s1l;
            float p34 = s1i * sP23[j * 64 + lane] + sR[OFF2 + row] * p22lane;
            float p44 = s1i * sR[j] * p22lane;
            pool4[r] += r4[r] - 0.5f * p24 + (1.0f / 3.0f) * p34 - 0.25f * p44;
        }
#pragma unroll
        for (int q = 0; q < 2; q++) {
            int m3 = tid + 256 * q;
            int i3 = m3 >> 6;
            pool3[q] += r3v[q] - 0.5f * sP23[m3] + (1.0f / 3.0f) * sR[i3] * p22lane;
        }
        if (tid < 64) pool2 += r2v - 0.5f * sR[tid >> 3] * sR[tid & 7];
        if (tid < 8)  pool1 += r1;
    }

    const float sc = 1.0f / (float)NCH;
    float* pb = pooled + (size_t)b * MEM;
#pragma unroll
    for (int r = 0; r < 16; r++) {
        int row = w + 4 * r;
        atomicAdd(&pb[OFF4 + row * 64 + lane], pool4[r] * sc);
    }
    atomicAdd(&pb[OFF3 + tid], pool3[0] * sc);
    atomicAdd(&pb[OFF3 + 256 + tid], pool3[1] * sc);
    if (tid < 64) atomicAdd(&pb[OFF2 + tid], pool2 * sc);
    if (tid < 8)  atomicAdd(&pb[tid], pool1 * sc);
}

// ------------------------------------------------ zero pooled + hbuf
#define ZN (8 * MEM + 8 * 256)
__global__ __launch_bounds__(256) void zero_kernel(float* __restrict__ buf) {
    int i = blockIdx.x * 256 + threadIdx.x;
    if (i < ZN) buf[i] = 0.0f;
}

// ------------------------------------------------ MLP
__global__ __launch_bounds__(256) void gemv1_kernel(const float* __restrict__ pooled,
                                                    const float* __restrict__ W1,
                                                    float* __restrict__ hbuf) {
    int kc = blockIdx.x;
    int tid = threadIdx.x;
    int k0 = kc * 32;
    __shared__ float sp[8][32];
    {
        int b = tid >> 5, kk = tid & 31;
        sp[b][kk] = (k0 + kk < MEM) ? pooled[b * MEM + k0 + kk] : 0.0f;
    }
    __syncthreads();
    float acc[8];
#pragma unroll
    for (int b = 0; b < 8; b++) acc[b] = 0.0f;
    int kend = (k0 + 32 < MEM) ? (k0 + 32) : MEM;
    for (int k = k0; k < kend; k++) {
        float wv = W1[(size_t)k * 256 + tid];
#pragma unroll
        for (int b = 0; b < 8; b++) acc[b] += sp[b][k - k0] * wv;
    }
#pragma unroll
    for (int b = 0; b < 8; b++) atomicAdd(&hbuf[b * 256 + tid], acc[b]);
}

__global__ __launch_bounds__(256) void final_kernel(const float* __restrict__ hbuf,
                                                    const float* __restrict__ b1,
                                                    const float* __restrict__ W2,
                                                    const float* __restrict__ b2,
                                                    float* __restrict__ outp) {
    int b = blockIdx.x;
    int tid = threadIdx.x;
    float v = hbuf[b * 256 + tid] + b1[tid];
    v = fmaxf(v, 0.0f) * W2[tid];
    __shared__ float sRed[256];
    sRed[tid] = v;
    __syncthreads();
    for (int s = 128; s > 0; s >>= 1) {
        if (tid < s) sRed[tid] += sRed[tid + s];
        __syncthreads();
    }
    if (tid == 0) outp[b] = sRed[0] + b2[0];
}

// ------------------------------------------------ launch
extern "C" void kernel_launch(void* const* d_in, const int* in_sizes, int n_in,
                              void* d_out, int out_size, void* d_ws, size_t ws_size,
                              hipStream_t stream) {
    const float* x  = (const float*)d_in[0];
    const float* W1 = (const float*)d_in[1];
    const float* b1 = (const float*)d_in[2];
    const float* W2 = (const float*)d_in[3];
    const float* b2 = (const float*)d_in[4];
    float* out = (float*)d_out;

    float* ws = (float*)d_ws;
    float* Q      = ws;                          // 1024*MEM
    float* P      = Q + (size_t)1024 * MEM;      // 256*MEM
    float* pooled = P + (size_t)256 * MEM;       // 8*MEM
    float* hbuf   = pooled + 8 * MEM;            // 8*256  (pooled+hbuf zeroed together)

    zero_kernel<<<(ZN + 255) / 256, 256, 0, stream>>>(pooled);
    group_sig_kernel<<<256, 256, 0, stream>>>(x, Q);
    scan_fold_kernel<<<8, 256, 0, stream>>>(Q, P);
    apply_log_pool_kernel<<<256, 256, 0, stream>>>(Q, P, pooled);
    gemv1_kernel<<<147, 256, 0, stream>>>(pooled, W1, hbuf);
    final_kernel<<<8, 256, 0, stream>>>(hbuf, b1, W2, b2, out);
}

// Round 4
// 136.620 us; speedup vs baseline: 1.4118x; 1.4118x over previous
//
#include <hip/hip_runtime.h>

// BLAMem: truncated tensor-algebra (depth 4, C=8) log-signature memory.
// Identities:
//  (1) BCH-prefix-scan of chunk log-sigs == ta_log of ta_mul-prefix-scan of chunk sigs.
//  (2) Chen fold over a 16-step chunk has a closed parallel form (group_sig).
//  (3) ta_mul prefix over group totals is lower-triangular: with exclusive prefixes
//      p_i of levels < k known, level-k increments T_k[g] = t_k[g] + sum_i p_i[g] (x) t_{k-i}[g]
//      are independent across g, and p_k = plain prefix-sum(T_k). -> 4 cascaded prefix sums.

#define MEM   4680   // 8 + 64 + 512 + 4096
#define OFF2  8
#define OFF3  72
#define OFF4  584
#define NCH   128
#define NG    32     // groups per batch
#define LCH   4      // chunks per group
#define TLEN  2048
#define GSTR  20     // G-table stride (floats): conflict-free b128 reads across kq

// ------------------------------------------------ group sigs (parallel-prefix Chen)
__global__ __launch_bounds__(256) void group_sig_kernel(const float* __restrict__ x,
                                                        float* __restrict__ Q) {
    int blk = blockIdx.x;
    int b = blk >> 5, g = blk & 31;
    int tid = threadIdx.x;
    int lane = tid & 63, w = tid >> 6;
    int kq = lane >> 3, lq = lane & 7;

    __shared__ float sInc[64 * 8];
    __shared__ __attribute__((aligned(16))) float sG[512 * GSTR];  // 40 KB
    __shared__ float sA[MEM];
    __shared__ float loc3[512];
    __shared__ float loc2[64];
    __shared__ float loc1[8];

    for (int e = tid; e < 64 * 8; e += 256) {
        int s = e >> 3, c = e & 7;
        int t = g * 64 + s;
        float v;
        if (c < 7) {
            float cur  = x[(b * TLEN + t) * 7 + c];
            float prev = (t > 0) ? x[(b * TLEN + t - 1) * 7 + c] : 0.0f;
            v = cur - prev;
        } else {
            v = (t > 0) ? (1.0f / 2047.0f) : 0.0f;
        }
        sInc[e] = v;
    }
    for (int m = tid; m < MEM; m += 256) sA[m] = 0.0f;
    __syncthreads();

    for (int c = 0; c < LCH; c++) {
        const float* dch = &sInc[c * 128];  // 16 steps x 8 channels

        int pos1 = tid, pos2 = tid + 256;
        int i1 = pos1 >> 6, j1 = (pos1 >> 3) & 7, k1 = pos1 & 7;
        int i2 = pos2 >> 6;
        float p1a = 0.0f, l2a = 0.0f, l3a = 0.0f;
        float p1b = 0.0f, l2b = 0.0f, l3b = 0.0f;
        float ga[16], gb[16];
#pragma unroll
        for (int t = 0; t < 16; t++) {
            float di1 = dch[t * 8 + i1], di2 = dch[t * 8 + i2];
            float dj = dch[t * 8 + j1], dk = dch[t * 8 + k1];
            ga[t] = l3a + dk * (l2a * 0.5f + dj * (p1a * (1.0f / 6.0f) + di1 * (1.0f / 24.0f)));
            gb[t] = l3b + dk * (l2b * 0.5f + dj * (p1b * (1.0f / 6.0f) + di2 * (1.0f / 24.0f)));
            l3a += dk * (l2a + dj * (p1a * 0.5f + di1 * (1.0f / 6.0f)));
            l3b += dk * (l2b + dj * (p1b * 0.5f + di2 * (1.0f / 6.0f)));
            l2a += p1a * dj + di1 * dj * 0.5f;
            l2b += p1b * dj + di2 * dj * 0.5f;
            p1a += di1;
            p1b += di2;
        }
        {
            float4* gp1 = (float4*)&sG[pos1 * GSTR];
            float4* gp2 = (float4*)&sG[pos2 * GSTR];
            gp1[0] = make_float4(ga[0], ga[1], ga[2], ga[3]);
            gp1[1] = make_float4(ga[4], ga[5], ga[6], ga[7]);
            gp1[2] = make_float4(ga[8], ga[9], ga[10], ga[11]);
            gp1[3] = make_float4(ga[12], ga[13], ga[14], ga[15]);
            gp2[0] = make_float4(gb[0], gb[1], gb[2], gb[3]);
            gp2[1] = make_float4(gb[4], gb[5], gb[6], gb[7]);
            gp2[2] = make_float4(gb[8], gb[9], gb[10], gb[11]);
            gp2[3] = make_float4(gb[12], gb[13], gb[14], gb[15]);
        }
        loc3[pos1] = l3a;
        loc3[pos2] = l3b;
        if (k1 == 0) { loc2[pos1 >> 3] = l2a; loc2[pos2 >> 3] = l2b; }
        if ((pos1 & 63) == 0) { loc1[i1] = p1a; loc1[i2] = p1b; }
        __syncthreads();

        float dl[16];
#pragma unroll
        for (int t = 0; t < 16; t++) dl[t] = dch[t * 8 + lq];

        float r4[16];
#pragma unroll
        for (int r = 0; r < 16; r++) {
            int row = w + 4 * r;
            int i = row >> 3, j = row & 7;
            int m = row * 64 + lane;
            const float4* gp = (const float4*)&sG[(row * 8 + kq) * GSTR];
            float4 g0 = gp[0], g1 = gp[1], g2 = gp[2], g3 = gp[3];
            float acc = g0.x * dl[0] + g0.y * dl[1] + g0.z * dl[2] + g0.w * dl[3]
                      + g1.x * dl[4] + g1.y * dl[5] + g1.z * dl[6] + g1.w * dl[7]
                      + g2.x * dl[8] + g2.y * dl[9] + g2.z * dl[10] + g2.w * dl[11]
                      + g3.x * dl[12] + g3.y * dl[13] + g3.z * dl[14] + g3.w * dl[15];
            r4[r] = sA[OFF4 + m] + acc
                  + sA[i] * loc3[j * 64 + lane]
                  + sA[OFF2 + row] * loc2[lane]
                  + sA[OFF3 + row * 8 + kq] * loc1[lq];
        }
        float r3[2];
#pragma unroll
        for (int q = 0; q < 2; q++) {
            int m3 = tid + 256 * q;
            float l3v = (q == 0) ? l3a : l3b;
            r3[q] = sA[OFF3 + m3] + l3v
                  + sA[m3 >> 6] * loc2[m3 & 63]
                  + sA[OFF2 + (m3 >> 3)] * loc1[m3 & 7];
        }
        float r2v = 0.0f, r1v = 0.0f;
        if (tid < 64) r2v = sA[OFF2 + tid] + loc2[tid] + sA[tid >> 3] * loc1[tid & 7];
        if (tid < 8)  r1v = sA[tid] + loc1[tid];
        __syncthreads();

        size_t qbase = (size_t)(blk * LCH + c) * MEM;
#pragma unroll
        for (int r = 0; r < 16; r++) {
            int row = w + 4 * r;
            int m = row * 64 + lane;
            sA[OFF4 + m] = r4[r];
            Q[qbase + OFF4 + m] = r4[r];
        }
        sA[OFF3 + tid] = r3[0];       Q[qbase + OFF3 + tid] = r3[0];
        sA[OFF3 + 256 + tid] = r3[1]; Q[qbase + OFF3 + 256 + tid] = r3[1];
        if (tid < 64) { sA[OFF2 + tid] = r2v; Q[qbase + OFF2 + tid] = r2v; }
        if (tid < 8)  { sA[tid] = r1v;        Q[qbase + tid] = r1v; }
        __syncthreads();
    }
}

// ------------------------------------------------ cascade scan, levels 1..3
// block=b. Exclusive prefixes of group totals, levels 1-3, written into P rows.
__global__ __launch_bounds__(256) void scan_low_kernel(const float* __restrict__ Q,
                                                       float* __restrict__ P) {
    int b = blockIdx.x;
    int tid = threadIdx.x;

    __shared__ float st1[NG][8];
    __shared__ float sp1[NG][8];
    __shared__ float st2[NG][64];
    __shared__ float sp2[NG][64];

    // load totals levels 1,2
    {
        int g = tid >> 3, i = tid & 7;
        st1[g][i] = Q[((size_t)((b * NG + g) * LCH + 3)) * MEM + i];
    }
    for (int m = tid; m < NG * 64; m += 256) {
        int g = m >> 6, e = m & 63;
        st2[g][e] = Q[((size_t)((b * NG + g) * LCH + 3)) * MEM + OFF2 + e];
    }
    __syncthreads();

    // p1 exclusive prefix
    if (tid < 8) {
        float acc = 0.0f;
        for (int g = 0; g < NG; g++) { sp1[g][tid] = acc; acc += st1[g][tid]; }
    }
    __syncthreads();
    // p2 exclusive prefix: T2[g] = t2[g] + p1[g] (x) t1[g]
    if (tid < 64) {
        int i = tid >> 3, k = tid & 7;
        float acc = 0.0f;
        for (int g = 0; g < NG; g++) {
            sp2[g][tid] = acc;
            acc += st2[g][tid] + sp1[g][i] * st1[g][k];
        }
    }
    __syncthreads();

    // write P levels 1,2
    {
        int g = tid >> 3, i = tid & 7;
        P[(size_t)(b * NG + g) * MEM + i] = sp1[g][i];
    }
    for (int m = tid; m < NG * 64; m += 256) {
        int g = m >> 6, e = m & 63;
        P[(size_t)(b * NG + g) * MEM + OFF2 + e] = sp2[g][e];
    }

    // p3: per-thread register prefix over g, 2 positions/thread, streamed to P
    int m1 = tid, m2 = tid + 256;
    int i1 = m1 >> 6, jk1 = m1 & 63, ij1 = m1 >> 3, k1 = m1 & 7;
    int i2 = m2 >> 6, jk2 = m2 & 63, ij2 = m2 >> 3, k2 = m2 & 7;
    float acc1 = 0.0f, acc2 = 0.0f;
#pragma unroll 4
    for (int g = 0; g < NG; g++) {
        size_t prow = (size_t)(b * NG + g) * MEM;
        size_t qrow = (size_t)((b * NG + g) * LCH + 3) * MEM;
        P[prow + OFF3 + m1] = acc1;
        P[prow + OFF3 + m2] = acc2;
        acc1 += Q[qrow + OFF3 + m1] + sp1[g][i1] * st2[g][jk1] + sp2[g][ij1] * st1[g][k1];
        acc2 += Q[qrow + OFF3 + m2] + sp1[g][i2] * st2[g][jk2] + sp2[g][ij2] * st1[g][k2];
    }
}

// ------------------------------------------------ cascade scan, level 4
// grid = 8 b x 16 slices; thread owns one level-4 position m = slice*256+tid.
// T4[g] = t4 + p1(x)t3 + p2(x)t2 + p3(x)t1 ; p4 = prefix-sum -> P level 4.
__global__ __launch_bounds__(256) void scan_l4_kernel(const float* __restrict__ Q,
                                                      float* __restrict__ P) {
    int bx = blockIdx.x;
    int b = bx >> 4, s = bx & 15;
    int m = s * 256 + threadIdx.x;
    int i = m >> 9, jkl = m & 511, ij = m >> 6, ijk = m >> 3, kl = m & 63, l = m & 7;

    float acc = 0.0f;
#pragma unroll 4
    for (int g = 0; g < NG; g++) {
        size_t prow = (size_t)(b * NG + g) * MEM;
        size_t qrow = (size_t)((b * NG + g) * LCH + 3) * MEM;
        P[prow + OFF4 + m] = acc;
        acc += Q[qrow + OFF4 + m]
             + P[prow + i] * Q[qrow + OFF3 + jkl]
             + P[prow + OFF2 + ij] * Q[qrow + OFF2 + kl]
             + P[prow + OFF3 + ijk] * Q[qrow + l];
    }
}

// ------------------------------------------------ apply prefix + log + pooled atomics
__global__ __launch_bounds__(256) void apply_log_pool_kernel(const float* __restrict__ Q,
                                                             const float* __restrict__ P,
                                                             float* __restrict__ pooled) {
    int blk = blockIdx.x;
    int b = blk >> 5;
    int tid = threadIdx.x;
    int lane = tid & 63, w = tid >> 6;
    int kq = lane >> 3, lq = lane & 7;

    __shared__ float sA[MEM];
    __shared__ float sB[MEM];
    __shared__ float sR[OFF4];
    __shared__ float sP23[512];

    {
        size_t pbase = (size_t)blk * MEM;
        const float4* src = (const float4*)(P + pbase);
        float4* dst = (float4*)sA;
        for (int m = tid; m < MEM / 4; m += 256) dst[m] = src[m];
    }

    float pool4[16];
#pragma unroll
    for (int r = 0; r < 16; r++) pool4[r] = 0.0f;
    float pool3[2] = {0.0f, 0.0f};
    float pool2 = 0.0f, pool1 = 0.0f;

    for (int c = 0; c < LCH; c++) {
        __syncthreads();
        {
            size_t baseQ = (size_t)(blk * LCH + c) * MEM;
            const float4* src = (const float4*)(Q + baseQ);
            float4* dst = (float4*)sB;
            for (int m = tid; m < MEM / 4; m += 256) dst[m] = src[m];
        }
        __syncthreads();

        float b1l = sB[lq];
        float b2lane = sB[OFF2 + lane];

        float r1 = 0.0f, r2v = 0.0f;
        float r3v[2];
#pragma unroll
        for (int q = 0; q < 2; q++) {
            int m3 = tid + 256 * q;
            r3v[q] = sA[OFF3 + m3] + sB[OFF3 + m3]
                   + sA[m3 >> 6] * sB[OFF2 + (m3 & 63)]
                   + sA[OFF2 + (m3 >> 3)] * sB[m3 & 7];
        }
        if (tid < 64) r2v = sA[OFF2 + tid] + sB[OFF2 + tid] + sA[tid >> 3] * sB[tid & 7];
        if (tid < 8)  r1 = sA[tid] + sB[tid];

        float r4[16];
#pragma unroll
        for (int r = 0; r < 16; r++) {
            int row = w + 4 * r;
            int i = row >> 3, j = row & 7;
            int m = row * 64 + lane;
            r4[r] = sA[OFF4 + m] + sB[OFF4 + m]
                  + sA[i] * sB[OFF3 + j * 64 + lane]
                  + sA[OFF2 + row] * b2lane
                  + sA[OFF3 + row * 8 + kq] * b1l;
        }

#pragma unroll
        for (int q = 0; q < 2; q++) sR[OFF3 + tid + 256 * q] = r3v[q];
        if (tid < 64) sR[OFF2 + tid] = r2v;
        if (tid < 8)  sR[tid] = r1;
        __syncthreads();

#pragma unroll
        for (int q = 0; q < 2; q++) {
            int m3 = tid + 256 * q;
            int i = m3 >> 6;
            sP23[m3] = sR[i] * sR[OFF2 + (m3 & 63)]
                     + sR[OFF2 + i * 8 + ((m3 >> 3) & 7)] * sR[m3 & 7];
        }
        __syncthreads();

        float s1l = sR[lq];
        float s2lane = sR[OFF2 + lane];
        float p22lane = sR[kq] * sR[lq];
#pragma unroll
        for (int r = 0; r < 16; r++) {
            int row = w + 4 * r;
            int i = row >> 3, j = row & 7;
            float s1i = sR[i];
            float p24 = s1i * sR[OFF3 + j * 64 + lane] + sR[OFF2 + row] * s2lane
                      + sR[OFF3 + row * 8 + kq] * s1l;
            float p34 = s1i * sP23[j * 64 + lane] + sR[OFF2 + row] * p22lane;
            float p44 = s1i * sR[j] * p22lane;
            pool4[r] += r4[r] - 0.5f * p24 + (1.0f / 3.0f) * p34 - 0.25f * p44;
        }
#pragma unroll
        for (int q = 0; q < 2; q++) {
            int m3 = tid + 256 * q;
            int i3 = m3 >> 6;
            pool3[q] += r3v[q] - 0.5f * sP23[m3] + (1.0f / 3.0f) * sR[i3] * p22lane;
        }
        if (tid < 64) pool2 += r2v - 0.5f * sR[tid >> 3] * sR[tid & 7];
        if (tid < 8)  pool1 += r1;
    }

    const float sc = 1.0f / (float)NCH;
    float* pb = pooled + (size_t)b * MEM;
#pragma unroll
    for (int r = 0; r < 16; r++) {
        int row = w + 4 * r;
        atomicAdd(&pb[OFF4 + row * 64 + lane], pool4[r] * sc);
    }
    atomicAdd(&pb[OFF3 + tid], pool3[0] * sc);
    atomicAdd(&pb[OFF3 + 256 + tid], pool3[1] * sc);
    if (tid < 64) atomicAdd(&pb[OFF2 + tid], pool2 * sc);
    if (tid < 8)  atomicAdd(&pb[tid], pool1 * sc);
}

// ------------------------------------------------ zero pooled + hbuf
#define ZN (8 * MEM + 8 * 256)
__global__ __launch_bounds__(256) void zero_kernel(float* __restrict__ buf) {
    int i = blockIdx.x * 256 + threadIdx.x;
    if (i < ZN) buf[i] = 0.0f;
}

// ------------------------------------------------ MLP
__global__ __launch_bounds__(256) void gemv1_kernel(const float* __restrict__ pooled,
                                                    const float* __restrict__ W1,
                                                    float* __restrict__ hbuf) {
    int kc = blockIdx.x;
    int tid = threadIdx.x;
    int k0 = kc * 32;
    __shared__ float sp[8][32];
    {
        int b = tid >> 5, kk = tid & 31;
        sp[b][kk] = (k0 + kk < MEM) ? pooled[b * MEM + k0 + kk] : 0.0f;
    }
    __syncthreads();
    float acc[8];
#pragma unroll
    for (int b = 0; b < 8; b++) acc[b] = 0.0f;
    int kend = (k0 + 32 < MEM) ? (k0 + 32) : MEM;
    for (int k = k0; k < kend; k++) {
        float wv = W1[(size_t)k * 256 + tid];
#pragma unroll
        for (int b = 0; b < 8; b++) acc[b] += sp[b][k - k0] * wv;
    }
#pragma unroll
    for (int b = 0; b < 8; b++) atomicAdd(&hbuf[b * 256 + tid], acc[b]);
}

__global__ __launch_bounds__(256) void final_kernel(const float* __restrict__ hbuf,
                                                    const float* __restrict__ b1,
                                                    const float* __restrict__ W2,
                                                    const float* __restrict__ b2,
                                                    float* __restrict__ outp) {
    int b = blockIdx.x;
    int tid = threadIdx.x;
    float v = hbuf[b * 256 + tid] + b1[tid];
    v = fmaxf(v, 0.0f) * W2[tid];
    __shared__ float sRed[256];
    sRed[tid] = v;
    __syncthreads();
    for (int s = 128; s > 0; s >>= 1) {
        if (tid < s) sRed[tid] += sRed[tid + s];
        __syncthreads();
    }
    if (tid == 0) outp[b] = sRed[0] + b2[0];
}

// ------------------------------------------------ launch
extern "C" void kernel_launch(void* const* d_in, const int* in_sizes, int n_in,
                              void* d_out, int out_size, void* d_ws, size_t ws_size,
                              hipStream_t stream) {
    const float* x  = (const float*)d_in[0];
    const float* W1 = (const float*)d_in[1];
    const float* b1 = (const float*)d_in[2];
    const float* W2 = (const float*)d_in[3];
    const float* b2 = (const float*)d_in[4];
    float* out = (float*)d_out;

    float* ws = (float*)d_ws;
    float* Q      = ws;                          // 1024*MEM
    float* P      = Q + (size_t)1024 * MEM;      // 256*MEM
    float* pooled = P + (size_t)256 * MEM;       // 8*MEM
    float* hbuf   = pooled + 8 * MEM;            // 8*256

    zero_kernel<<<(ZN + 255) / 256, 256, 0, stream>>>(pooled);
    group_sig_kernel<<<256, 256, 0, stream>>>(x, Q);
    scan_low_kernel<<<8, 256, 0, stream>>>(Q, P);
    scan_l4_kernel<<<128, 256, 0, stream>>>(Q, P);
    apply_log_pool_kernel<<<256, 256, 0, stream>>>(Q, P, pooled);
    gemv1_kernel<<<147, 256, 0, stream>>>(pooled, W1, hbuf);
    final_kernel<<<8, 256, 0, stream>>>(hbuf, b1, W2, b2, out);
}

// Round 5
// 127.543 us; speedup vs baseline: 1.5123x; 1.0712x over previous
//
#include <hip/hip_runtime.h>

// BLAMem: truncated tensor-algebra (depth 4, C=8) log-signature memory.
// Identities:
//  (1) BCH-prefix-scan of chunk log-sigs == ta_log of ta_mul-prefix-scan of chunk sigs.
//  (2) Chen fold over a 16-step chunk has a closed parallel form (group_sig).
//  (3) ta_mul prefix over group totals is lower-triangular: with exclusive prefixes
//      p_i of levels < k known, level-k increments are independent across g, and
//      p_k = plain prefix-sum. -> cascaded prefix sums, parallel across positions.

#define MEM   4680   // 8 + 64 + 512 + 4096
#define OFF2  8
#define OFF3  72
#define OFF4  584
#define NCH   128
#define NG    32     // groups per batch
#define LCH   4      // chunks per group
#define TLEN  2048
#define GSTR  20     // G-table stride (floats): conflict-free b128 reads across kq
#define ZN    (8 * MEM + 8 * 256)   // pooled + hbuf zero region

// ------------------------------------------------ group sigs (parallel-prefix Chen)
// block=(b,g). Also zeroes a slice of pooled/hbuf (fused zero_kernel).
__global__ __launch_bounds__(256) void group_sig_kernel(const float* __restrict__ x,
                                                        float* __restrict__ Q,
                                                        float* __restrict__ zbuf) {
    int blk = blockIdx.x;
    int b = blk >> 5, g = blk & 31;
    int tid = threadIdx.x;
    int lane = tid & 63, w = tid >> 6;
    int kq = lane >> 3, lq = lane & 7;

    // fused zero of pooled+hbuf (consumed 2+ dispatches later)
    for (int i = blk * 256 + tid; i < ZN; i += 256 * 256) zbuf[i] = 0.0f;

    __shared__ float sInc[64 * 8];
    __shared__ __attribute__((aligned(16))) float sG[512 * GSTR];  // 40 KB
    __shared__ float sA[MEM];
    __shared__ float loc3[512];
    __shared__ float loc2[64];
    __shared__ float loc1[8];

    for (int e = tid; e < 64 * 8; e += 256) {
        int s = e >> 3, c = e & 7;
        int t = g * 64 + s;
        float v;
        if (c < 7) {
            float cur  = x[(b * TLEN + t) * 7 + c];
            float prev = (t > 0) ? x[(b * TLEN + t - 1) * 7 + c] : 0.0f;
            v = cur - prev;
        } else {
            v = (t > 0) ? (1.0f / 2047.0f) : 0.0f;
        }
        sInc[e] = v;
    }
    for (int m = tid; m < MEM; m += 256) sA[m] = 0.0f;
    __syncthreads();

    for (int c = 0; c < LCH; c++) {
        const float* dch = &sInc[c * 128];  // 16 steps x 8 channels

        int pos1 = tid, pos2 = tid + 256;
        int i1 = pos1 >> 6, j1 = (pos1 >> 3) & 7, k1 = pos1 & 7;
        int i2 = pos2 >> 6;
        float p1a = 0.0f, l2a = 0.0f, l3a = 0.0f;
        float p1b = 0.0f, l2b = 0.0f, l3b = 0.0f;
        float ga[16], gb[16];
#pragma unroll
        for (int t = 0; t < 16; t++) {
            float di1 = dch[t * 8 + i1], di2 = dch[t * 8 + i2];
            float dj = dch[t * 8 + j1], dk = dch[t * 8 + k1];
            ga[t] = l3a + dk * (l2a * 0.5f + dj * (p1a * (1.0f / 6.0f) + di1 * (1.0f / 24.0f)));
            gb[t] = l3b + dk * (l2b * 0.5f + dj * (p1b * (1.0f / 6.0f) + di2 * (1.0f / 24.0f)));
            l3a += dk * (l2a + dj * (p1a * 0.5f + di1 * (1.0f / 6.0f)));
            l3b += dk * (l2b + dj * (p1b * 0.5f + di2 * (1.0f / 6.0f)));
            l2a += p1a * dj + di1 * dj * 0.5f;
            l2b += p1b * dj + di2 * dj * 0.5f;
            p1a += di1;
            p1b += di2;
        }
        {
            float4* gp1 = (float4*)&sG[pos1 * GSTR];
            float4* gp2 = (float4*)&sG[pos2 * GSTR];
            gp1[0] = make_float4(ga[0], ga[1], ga[2], ga[3]);
            gp1[1] = make_float4(ga[4], ga[5], ga[6], ga[7]);
            gp1[2] = make_float4(ga[8], ga[9], ga[10], ga[11]);
            gp1[3] = make_float4(ga[12], ga[13], ga[14], ga[15]);
            gp2[0] = make_float4(gb[0], gb[1], gb[2], gb[3]);
            gp2[1] = make_float4(gb[4], gb[5], gb[6], gb[7]);
            gp2[2] = make_float4(gb[8], gb[9], gb[10], gb[11]);
            gp2[3] = make_float4(gb[12], gb[13], gb[14], gb[15]);
        }
        loc3[pos1] = l3a;
        loc3[pos2] = l3b;
        if (k1 == 0) { loc2[pos1 >> 3] = l2a; loc2[pos2 >> 3] = l2b; }
        if ((pos1 & 63) == 0) { loc1[i1] = p1a; loc1[i2] = p1b; }
        __syncthreads();

        float dl[16];
#pragma unroll
        for (int t = 0; t < 16; t++) dl[t] = dch[t * 8 + lq];

        float r4[16];
#pragma unroll
        for (int r = 0; r < 16; r++) {
            int row = w + 4 * r;
            int i = row >> 3, j = row & 7;
            int m = row * 64 + lane;
            const float4* gp = (const float4*)&sG[(row * 8 + kq) * GSTR];
            float4 g0 = gp[0], g1 = gp[1], g2 = gp[2], g3 = gp[3];
            float acc = g0.x * dl[0] + g0.y * dl[1] + g0.z * dl[2] + g0.w * dl[3]
                      + g1.x * dl[4] + g1.y * dl[5] + g1.z * dl[6] + g1.w * dl[7]
                      + g2.x * dl[8] + g2.y * dl[9] + g2.z * dl[10] + g2.w * dl[11]
                      + g3.x * dl[12] + g3.y * dl[13] + g3.z * dl[14] + g3.w * dl[15];
            r4[r] = sA[OFF4 + m] + acc
                  + sA[i] * loc3[j * 64 + lane]
                  + sA[OFF2 + row] * loc2[lane]
                  + sA[OFF3 + row * 8 + kq] * loc1[lq];
        }
        float r3[2];
#pragma unroll
        for (int q = 0; q < 2; q++) {
            int m3 = tid + 256 * q;
            float l3v = (q == 0) ? l3a : l3b;
            r3[q] = sA[OFF3 + m3] + l3v
                  + sA[m3 >> 6] * loc2[m3 & 63]
                  + sA[OFF2 + (m3 >> 3)] * loc1[m3 & 7];
        }
        float r2v = 0.0f, r1v = 0.0f;
        if (tid < 64) r2v = sA[OFF2 + tid] + loc2[tid] + sA[tid >> 3] * loc1[tid & 7];
        if (tid < 8)  r1v = sA[tid] + loc1[tid];
        __syncthreads();

        size_t qbase = (size_t)(blk * LCH + c) * MEM;
#pragma unroll
        for (int r = 0; r < 16; r++) {
            int row = w + 4 * r;
            int m = row * 64 + lane;
            sA[OFF4 + m] = r4[r];
            Q[qbase + OFF4 + m] = r4[r];
        }
        sA[OFF3 + tid] = r3[0];       Q[qbase + OFF3 + tid] = r3[0];
        sA[OFF3 + 256 + tid] = r3[1]; Q[qbase + OFF3 + 256 + tid] = r3[1];
        if (tid < 64) { sA[OFF2 + tid] = r2v; Q[qbase + OFF2 + tid] = r2v; }
        if (tid < 8)  { sA[tid] = r1v;        Q[qbase + tid] = r1v; }
        __syncthreads();
    }
}

// ------------------------------------------------ fused cascade scan (all levels)
// grid = 8 b x 16 slices. Each block: p1/p2 prefixes in LDS (redundant per b),
// its own 32-wide p3 slice, then per-thread level-4 register prefix over g.
// Writes exclusive prefixes P (levels 1,2 by s==0 blocks; level-3/4 slices by all).
__global__ __launch_bounds__(256) void scan_fused_kernel(const float* __restrict__ Q,
                                                         float* __restrict__ P) {
    int bx = blockIdx.x;
    int b = bx >> 4, s = bx & 15;
    int tid = threadIdx.x;

    __shared__ float st1[NG][8];
    __shared__ float st2[NG][64];
    __shared__ float st3[NG][32];   // slice ijk in [s*32, s*32+32)
    __shared__ float sp1[NG][8];
    __shared__ float sp2[NG][64];
    __shared__ float sp3[NG][32];

    // Phase A: load group totals (levels 1,2 full; level-3 slice)
    {
        int g = tid >> 3, i = tid & 7;
        st1[g][i] = Q[((size_t)((b * NG + g) * LCH + 3)) * MEM + i];
    }
    for (int m = tid; m < NG * 64; m += 256) {
        int g = m >> 6, e = m & 63;
        st2[g][e] = Q[((size_t)((b * NG + g) * LCH + 3)) * MEM + OFF2 + e];
    }
    for (int m = tid; m < NG * 32; m += 256) {
        int g = m >> 5, e = m & 31;
        st3[g][e] = Q[((size_t)((b * NG + g) * LCH + 3)) * MEM + OFF3 + s * 32 + e];
    }
    __syncthreads();

    // Phase B: p1/p2 exclusive prefixes (tid<64); s==0 blocks also write P1/P2.
    if (tid < 64) {
        int i = tid >> 3, k = tid & 7;
        float p1acc = 0.0f, p2acc = 0.0f;
        for (int g = 0; g < NG; g++) {
            sp2[g][tid] = p2acc;
            if (k == 0) sp1[g][i] = p1acc;
            if (s == 0) {
                size_t prow = (size_t)(b * NG + g) * MEM;
                P[prow + OFF2 + tid] = p2acc;
                if (k == 0) P[prow + i] = p1acc;
            }
            p2acc += st2[g][tid] + p1acc * st1[g][k];
            p1acc += st1[g][i];
        }
    }
    __syncthreads();

    // Phase C: p3 slice prefix (tid<32); every block writes its P3 slice.
    if (tid < 32) {
        int ijk = s * 32 + tid;
        int i = ijk >> 6, jk = ijk & 63, ij = ijk >> 3, k = ijk & 7;
        float acc3 = 0.0f;
        for (int g = 0; g < NG; g++) {
            sp3[g][tid] = acc3;
            P[(size_t)(b * NG + g) * MEM + OFF3 + ijk] = acc3;
            acc3 += st3[g][tid] + sp1[g][i] * st2[g][jk] + sp2[g][ij] * st1[g][k];
        }
    }
    __syncthreads();

    // Phase D: level-4 register prefix, one position per thread.
    int m = s * 256 + tid;
    int i = m >> 9, jkl = m & 511, ij = m >> 6, ijk_l = tid >> 3, kl = m & 63, l = m & 7;
    float acc4 = 0.0f;
#pragma unroll 4
    for (int g = 0; g < NG; g++) {
        size_t prow = (size_t)(b * NG + g) * MEM;
        size_t qrow = (size_t)((b * NG + g) * LCH + 3) * MEM;
        P[prow + OFF4 + m] = acc4;
        acc4 += Q[qrow + OFF4 + m]
              + sp1[g][i] * Q[qrow + OFF3 + jkl]
              + sp2[g][ij] * st2[g][kl]
              + sp3[g][ijk_l] * st1[g][l];
    }
}

// ------------------------------------------------ apply prefix + log + pooled atomics
// block=(b,g). Stages P row + all 4 contiguous Q chunk rows in ONE burst (93.6 KB LDS),
// then computes with LDS-only barriers.
__global__ __launch_bounds__(256) void apply_log_pool_kernel(const float* __restrict__ Q,
                                                             const float* __restrict__ P,
                                                             float* __restrict__ pooled) {
    int blk = blockIdx.x;
    int b = blk >> 5;
    int tid = threadIdx.x;
    int lane = tid & 63, w = tid >> 6;
    int kq = lane >> 3, lq = lane & 7;

    __shared__ float sA[MEM];          // group exclusive prefix
    __shared__ float sB[LCH * MEM];    // 4 Q chunk rows (contiguous in global)
    __shared__ float sR[OFF4];         // R levels 1..3
    __shared__ float sP23[512];        // (R^2) level 3

    {
        const float4* srcP = (const float4*)(P + (size_t)blk * MEM);
        float4* dstA = (float4*)sA;
        for (int m = tid; m < MEM / 4; m += 256) dstA[m] = srcP[m];
        const float4* srcQ = (const float4*)(Q + (size_t)blk * LCH * MEM);
        float4* dstB = (float4*)sB;
        for (int m = tid; m < LCH * MEM / 4; m += 256) dstB[m] = srcQ[m];
    }
    __syncthreads();

    float pool4[16];
#pragma unroll
    for (int r = 0; r < 16; r++) pool4[r] = 0.0f;
    float pool3[2] = {0.0f, 0.0f};
    float pool2 = 0.0f, pool1 = 0.0f;

    for (int c = 0; c < LCH; c++) {
        const float* sBc = &sB[c * MEM];
        float b1l = sBc[lq];
        float b2lane = sBc[OFF2 + lane];

        float r1 = 0.0f, r2v = 0.0f;
        float r3v[2];
#pragma unroll
        for (int q = 0; q < 2; q++) {
            int m3 = tid + 256 * q;
            r3v[q] = sA[OFF3 + m3] + sBc[OFF3 + m3]
                   + sA[m3 >> 6] * sBc[OFF2 + (m3 & 63)]
                   + sA[OFF2 + (m3 >> 3)] * sBc[m3 & 7];
        }
        if (tid < 64) r2v = sA[OFF2 + tid] + sBc[OFF2 + tid] + sA[tid >> 3] * sBc[tid & 7];
        if (tid < 8)  r1 = sA[tid] + sBc[tid];

        float r4[16];
#pragma unroll
        for (int r = 0; r < 16; r++) {
            int row = w + 4 * r;
            int i = row >> 3, j = row & 7;
            int m = row * 64 + lane;
            r4[r] = sA[OFF4 + m] + sBc[OFF4 + m]
                  + sA[i] * sBc[OFF3 + j * 64 + lane]
                  + sA[OFF2 + row] * b2lane
                  + sA[OFF3 + row * 8 + kq] * b1l;
        }

        __syncthreads();   // previous iteration's sR/sP23 consumers done
#pragma unroll
        for (int q = 0; q < 2; q++) sR[OFF3 + tid + 256 * q] = r3v[q];
        if (tid < 64) sR[OFF2 + tid] = r2v;
        if (tid < 8)  sR[tid] = r1;
        __syncthreads();

#pragma unroll
        for (int q = 0; q < 2; q++) {
            int m3 = tid + 256 * q;
            int i = m3 >> 6;
            sP23[m3] = sR[i] * sR[OFF2 + (m3 & 63)]
                     + sR[OFF2 + i * 8 + ((m3 >> 3) & 7)] * sR[m3 & 7];
        }
        __syncthreads();

        float s1l = sR[lq];
        float s2lane = sR[OFF2 + lane];
        float p22lane = sR[kq] * sR[lq];
#pragma unroll
        for (int r = 0; r < 16; r++) {
            int row = w + 4 * r;
            int i = row >> 3, j = row & 7;
            float s1i = sR[i];
            float p24 = s1i * sR[OFF3 + j * 64 + lane] + sR[OFF2 + row] * s2lane
                      + sR[OFF3 + row * 8 + kq] * s1l;
            float p34 = s1i * sP23[j * 64 + lane] + sR[OFF2 + row] * p22lane;
            float p44 = s1i * sR[j] * p22lane;
            pool4[r] += r4[r] - 0.5f * p24 + (1.0f / 3.0f) * p34 - 0.25f * p44;
        }
#pragma unroll
        for (int q = 0; q < 2; q++) {
            int m3 = tid + 256 * q;
            int i3 = m3 >> 6;
            pool3[q] += r3v[q] - 0.5f * sP23[m3] + (1.0f / 3.0f) * sR[i3] * p22lane;
        }
        if (tid < 64) pool2 += r2v - 0.5f * sR[tid >> 3] * sR[tid & 7];
        if (tid < 8)  pool1 += r1;
    }

    const float sc = 1.0f / (float)NCH;
    float* pb = pooled + (size_t)b * MEM;
#pragma unroll
    for (int r = 0; r < 16; r++) {
        int row = w + 4 * r;
        atomicAdd(&pb[OFF4 + row * 64 + lane], pool4[r] * sc);
    }
    atomicAdd(&pb[OFF3 + tid], pool3[0] * sc);
    atomicAdd(&pb[OFF3 + 256 + tid], pool3[1] * sc);
    if (tid < 64) atomicAdd(&pb[OFF2 + tid], pool2 * sc);
    if (tid < 8)  atomicAdd(&pb[tid], pool1 * sc);
}

// ------------------------------------------------ MLP
__global__ __launch_bounds__(256) void gemv1_kernel(const float* __restrict__ pooled,
                                                    const float* __restrict__ W1,
                                                    float* __restrict__ hbuf) {
    int kc = blockIdx.x;
    int tid = threadIdx.x;
    int k0 = kc * 32;
    __shared__ float sp[8][32];
    {
        int b = tid >> 5, kk = tid & 31;
        sp[b][kk] = (k0 + kk < MEM) ? pooled[b * MEM + k0 + kk] : 0.0f;
    }
    __syncthreads();
    float acc[8];
#pragma unroll
    for (int b = 0; b < 8; b++) acc[b] = 0.0f;
    int kend = (k0 + 32 < MEM) ? (k0 + 32) : MEM;
    for (int k = k0; k < kend; k++) {
        float wv = W1[(size_t)k * 256 + tid];
#pragma unroll
        for (int b = 0; b < 8; b++) acc[b] += sp[b][k - k0] * wv;
    }
#pragma unroll
    for (int b = 0; b < 8; b++) atomicAdd(&hbuf[b * 256 + tid], acc[b]);
}

__global__ __launch_bounds__(256) void final_kernel(const float* __restrict__ hbuf,
                                                    const float* __restrict__ b1,
                                                    const float* __restrict__ W2,
                                                    const float* __restrict__ b2,
                                                    float* __restrict__ outp) {
    int b = blockIdx.x;
    int tid = threadIdx.x;
    float v = hbuf[b * 256 + tid] + b1[tid];
    v = fmaxf(v, 0.0f) * W2[tid];
    __shared__ float sRed[256];
    sRed[tid] = v;
    __syncthreads();
    for (int s = 128; s > 0; s >>= 1) {
        if (tid < s) sRed[tid] += sRed[tid + s];
        __syncthreads();
    }
    if (tid == 0) outp[b] = sRed[0] + b2[0];
}

// ------------------------------------------------ launch
extern "C" void kernel_launch(void* const* d_in, const int* in_sizes, int n_in,
                              void* d_out, int out_size, void* d_ws, size_t ws_size,
                              hipStream_t stream) {
    const float* x  = (const float*)d_in[0];
    const float* W1 = (const float*)d_in[1];
    const float* b1 = (const float*)d_in[2];
    const float* W2 = (const float*)d_in[3];
    const float* b2 = (const float*)d_in[4];
    float* out = (float*)d_out;

    float* ws = (float*)d_ws;
    float* Q      = ws;                          // 1024*MEM
    float* P      = Q + (size_t)1024 * MEM;      // 256*MEM
    float* pooled = P + (size_t)256 * MEM;       // 8*MEM
    float* hbuf   = pooled + 8 * MEM;            // 8*256 (zeroed inside group_sig)

    group_sig_kernel<<<256, 256, 0, stream>>>(x, Q, pooled);
    scan_fused_kernel<<<128, 256, 0, stream>>>(Q, P);
    apply_log_pool_kernel<<<256, 256, 0, stream>>>(Q, P, pooled);
    gemv1_kernel<<<147, 256, 0, stream>>>(pooled, W1, hbuf);
    final_kernel<<<8, 256, 0, stream>>>(hbuf, b1, W2, b2, out);
}